// Round 9
// baseline (18.985 us; speedup 1.0000x reference)
//
#include <hip/hip_runtime.h>
#include <math.h>

// Problem constants
constexpr int kNB   = 16;
constexpr int kNA   = 5;
constexpr int kNC   = 80;
constexpr int kNH   = 64;
constexpr int kNW   = 64;
constexpr int kMAXT = 50;
constexpr int kCH    = 5 + kNC;          // 85
constexpr int kPLANE = kNH * kNW;        // 4096
constexpr int kCELLS_B = kNA * kPLANE;   // 20480
constexpr int kBLK  = 1024;              // 16 waves
constexpr int kBPB  = kCELLS_B / kBLK;   // 20 blocks per batch
constexpr int kGRID = kNB * kBPB;        // 320 (all co-resident)
constexpr float kOBJ = 5.0f;
constexpr unsigned kREADY = 0x9E3779B9u; // != 0, != 0xAAAAAAAA poison

// Record layout (16 floats / target):
//  [0..3] x1,x2,y1,y2   [4] 0.6*garea  [5] cell(int bits)  [6] owner  [7] pad
//  [8..11] t0..t3       [12] tconf     [13] tcls           [14..15] pad
constexpr int kRECF = 16;
constexpr int kRECB = kMAXT * kRECF;     // 800 floats per batch

__device__ __forceinline__ float frcp(float x) { return __builtin_amdgcn_rcpf(x); }
__device__ __forceinline__ float fsig(float x) { return frcp(1.0f + __expf(-x)); }

// ------------- Kernel 1: per-target records, once per batch (16 x 64) -------------
__global__ __launch_bounds__(64) void k_targets(const float* __restrict__ out,
                                                const float* __restrict__ target,
                                                const float* __restrict__ anchors,
                                                float* __restrict__ recG,
                                                int* __restrict__ nvArr) {
    const int b = blockIdx.x, t = threadIdx.x;

    float c0 = 0.f, x = 0.f, y = 0.f, w = 0.f, h = 0.f;
    if (t < kMAXT) {
        const float* tp = target + (b * kMAXT + t) * 5;
        c0 = tp[0]; x = tp[1]; y = tp[2]; w = tp[3]; h = tp[4];
    }
    // validity prefix (cumprod of x!=0): nv = first zero-x index
    unsigned long long m = __ballot(x != 0.0f);
    int nv = (int)__builtin_ctzll(~m);
    if (t == 0) nvArr[b] = nv;

    const bool act = (t < nv);
    int cell = -1, gi = 0, gj = 0, bn = 0;
    float gx = 0, gy = 0, gw = 0, gh = 0, aw = 1.f, ah = 1.f;
    if (act) {
        gx = x * kNW; gy = y * kNH; gw = w * kNW; gh = h * kNH;
        float best = -1.0f;                        // first max wins (jnp.argmax)
        for (int n = 0; n < kNA; ++n) {
            float aw_ = anchors[2 * n], ah_ = anchors[2 * n + 1];
            float inter = fminf(gw, aw_) * fminf(gh, ah_);
            float uni = gw * gh + aw_ * ah_ - inter;
            float r = inter / uni;
            if (r > best) { best = r; bn = n; }
        }
        aw = anchors[2 * bn]; ah = anchors[2 * bn + 1];
        gi = (int)gx; gi = gi < 0 ? 0 : (gi > kNW - 1 ? kNW - 1 : gi);
        gj = (int)gy; gj = gj < 0 ? 0 : (gj > kNH - 1 ? kNH - 1 : gj);
        cell = bn * kPLANE + gj * kNW + gi;
    }
    // owner = last target writing this cell (scatter last-write-wins)
    bool owner = act;
    for (int t2 = 0; t2 < kMAXT; ++t2) {
        int c2 = __shfl(cell, t2, 64);
        if (act && t2 > t && c2 == cell) owner = false;   // lanes >= nv have cell=-1
    }
    if (act) {
        const float* mb = out + ((size_t)(b * kNA + bn) * kCH) * kPLANE + gj * kNW + gi;
        float px = fsig(mb[0]) + (float)gi;
        float py = fsig(mb[kPLANE]) + (float)gj;
        float pw = __expf(mb[2 * kPLANE]) * aw;
        float ph = __expf(mb[3 * kPLANE]) * ah;
        float cw  = fminf(gx + 0.5f * gw, px + 0.5f * pw) - fmaxf(gx - 0.5f * gw, px - 0.5f * pw);
        float chh = fminf(gy + 0.5f * gh, py + 0.5f * ph) - fmaxf(gy - 0.5f * gh, py - 0.5f * ph);
        float inter = fmaxf(cw, 0.f) * fmaxf(chh, 0.f);
        float uni = gw * gh + pw * ph - inter;
        float iou = (inter > 0.f) ? inter / uni : 0.f;

        float* r = recG + b * kRECB + t * kRECF;
        r[0]  = gx - 0.5f * gw;  r[1]  = gx + 0.5f * gw;
        r[2]  = gy - 0.5f * gh;  r[3]  = gy + 0.5f * gh;
        r[4]  = 0.6f * gw * gh;  r[5]  = __int_as_float(cell);
        r[6]  = owner ? 1.f : 0.f; r[7] = 0.f;
        r[8]  = gx - (float)gi;  r[9]  = gy - (float)gj;
        r[10] = __logf(gw / aw); r[11] = __logf(gh / ah);
        r[12] = iou;             r[13] = c0;
        r[14] = 0.f;             r[15] = 0.f;
    }
}

// ------------- Kernel 2: per-cell loss + CE + in-kernel deterministic finale -------------
__global__ __launch_bounds__(1024) void k_fused(const float* __restrict__ out,
                                                const float* __restrict__ anchors,
                                                const float* __restrict__ recG,
                                                const int* __restrict__ nvArr,
                                                float* __restrict__ partials,
                                                unsigned* __restrict__ flags,
                                                float* __restrict__ outv) {
    __shared__ __align__(16) float srec[kRECB];
    __shared__ float wred[16];

    const int tid  = threadIdx.x;
    const int wave = tid >> 6;
    const int lane = tid & 63;
    const int b    = blockIdx.x / kBPB;
    const int blkb = blockIdx.x % kBPB;      // 0..19 within batch

    // ---------- Phase 0: issue per-cell channel loads + stage records (parallel) -------
    const int cidx = blkb * kBLK + tid;      // within-batch cell 0..20479 (== mycell)
    const int a    = cidx / kPLANE;          // block-uniform
    const int remp = cidx & (kPLANE - 1);
    const int i    = remp & (kNW - 1), j = remp >> 6;
    const float* ob = out + ((size_t)(b * kNA + a) * kCH) * kPLANE + remp;
    float o0 = ob[0];
    float o1 = ob[kPLANE];
    float o2 = ob[2 * kPLANE];
    float o3 = ob[3 * kPLANE];
    float o4 = ob[4 * kPLANE];

    if (tid < kRECB) srec[tid] = recG[b * kRECB + tid];   // one coalesced burst
    const int nv = nvArr[b];                              // uniform scalar load
    __syncthreads();

    // ---------- CE prep on waves 1-3 (read staged records, issue class loads) ----------
    float ceV0 = 0.f, ceV1 = -INFINITY, ceLt = 0.f;
    bool doCE = false;
    if (wave >= 1 && wave <= 3) {
        const int t_ce = blkb + kBPB * (wave - 1);        // 0..59 covers all 50
        if (t_ce < nv && srec[t_ce * kRECF + 6] != 0.f) {
            doCE = true;
            int cell = __float_as_int(srec[t_ce * kRECF + 5]);
            int bn = cell >> 12, pix = cell & (kPLANE - 1);
            int tcls = (int)srec[t_ce * kRECF + 13];
            const float* lg = out + ((size_t)(b * kNA + bn) * kCH + 5) * kPLANE + pix;
            ceV0 = lg[(size_t)lane * kPLANE];
            if (lane < kNC - 64) ceV1 = lg[(size_t)(64 + lane) * kPLANE];
            ceLt = lg[(size_t)tcls * kPLANE];
        }
    }

    // ---------- Phase C: per-cell loss ----------
    float tx   = fsig(o0);
    float ty   = fsig(o1);
    float tw   = o2;
    float th   = o3;
    float conf = fsig(o4);

    float aw = anchors[2 * a], ah = anchors[2 * a + 1];
    float pw = __expf(tw) * aw, ph = __expf(th) * ah;
    float px = tx + (float)i, py = ty + (float)j;
    float px1 = px - 0.5f * pw, px2 = px + 0.5f * pw;
    float py1 = py - 0.5f * ph, py2 = py + 0.5f * ph;
    float p06 = 0.6f * pw * ph;

    // iou > 0.6  <=>  max_t(1.6*inter - 0.6*garea) > 0.6*parea
    float flag = -INFINITY;
    int match = -1;                           // last matching t wins (scatter semantics)
    for (int t = 0; t < nv; ++t) {
        const float4 bx = *reinterpret_cast<const float4*>(srec + t * kRECF);
        const float2 gc = *reinterpret_cast<const float2*>(srec + t * kRECF + 4);
        float cw  = fminf(bx.y, px2) - fmaxf(bx.x, px1);
        float chh = fminf(bx.w, py2) - fmaxf(bx.z, py1);
        float inter = fmaxf(cw, 0.f) * fmaxf(chh, 0.f);
        flag = fmaxf(flag, fmaf(1.6f, inter, -gc.x));
        match = (__float_as_int(gc.y) == cidx) ? t : match;
    }

    float t0 = 0.5f, t1 = 0.5f, t2 = 0.f, t3 = 0.f, tconf = 0.f, cmask;
    if (match >= 0) {
        const float4 tt = *reinterpret_cast<const float4*>(srec + match * kRECF + 8);
        t0 = tt.x; t1 = tt.y; t2 = tt.z; t3 = tt.w;
        tconf = srec[match * kRECF + 12];
        cmask = kOBJ;
    } else {
        cmask = (flag > p06) ? 0.f : 1.f;
    }

    float dx = tx - t0, dy = ty - t1, dw = tw - t2, dh = th - t3, dc = conf - tconf;
    float loss = 0.5f * (dx * dx + dy * dy + dw * dw + dh * dh)
               + 0.5f * cmask * dc * dc;

    // ---------- Phase D: finish CE on waves 1-3 (wave-uniform per wave) ----------
    if (doCE) {
        float mx = fmaxf(ceV0, ceV1);
        #pragma unroll
        for (int off = 32; off > 0; off >>= 1) mx = fmaxf(mx, __shfl_xor(mx, off, 64));
        float s = __expf(ceV0 - mx) + ((lane < kNC - 64) ? __expf(ceV1 - mx) : 0.f);
        #pragma unroll
        for (int off = 32; off > 0; off >>= 1) s += __shfl_xor(s, off, 64);
        if (lane == 0) loss += __logf(s) + mx - ceLt;
    }

    // ---------- Phase E: block partial -> distinct-address flag handshake ----------
    #pragma unroll
    for (int off = 32; off > 0; off >>= 1) loss += __shfl_down(loss, off, 64);
    if (lane == 0) wred[wave] = loss;
    __syncthreads();
    if (tid == 0) {
        float v = 0.f;
        #pragma unroll
        for (int w = 0; w < 16; ++w) v += wred[w];     // fixed order
        __hip_atomic_store(&partials[blockIdx.x], v, __ATOMIC_RELAXED, __HIP_MEMORY_SCOPE_AGENT);
        __hip_atomic_store(&flags[blockIdx.x], kREADY, __ATOMIC_RELEASE, __HIP_MEMORY_SCOPE_AGENT);
    }

    // ---------- Phase F: block 0 gathers all partials (deterministic order) ----------
    if (blockIdx.x == 0) {
        __syncthreads();                                // protect wred reuse
        float v = 0.f;
        if (tid < kGRID) {
            while (__hip_atomic_load(&flags[tid], __ATOMIC_ACQUIRE, __HIP_MEMORY_SCOPE_AGENT) != kREADY)
                __builtin_amdgcn_s_sleep(2);
            v = __hip_atomic_load(&partials[tid], __ATOMIC_RELAXED, __HIP_MEMORY_SCOPE_AGENT);
            // reset for the next call (stream-ordered; no overlap between calls)
            __hip_atomic_store(&flags[tid], 0u, __ATOMIC_RELAXED, __HIP_MEMORY_SCOPE_AGENT);
        }
        #pragma unroll
        for (int off = 32; off > 0; off >>= 1) v += __shfl_down(v, off, 64);
        if (lane == 0) wred[wave] = v;
        __syncthreads();
        if (tid == 0) {
            float s = 0.f;
            #pragma unroll
            for (int w = 0; w < 16; ++w) s += wred[w];  // fixed order (only waves 0-4 nonzero)
            outv[0] = s;
        }
    }
}

extern "C" void kernel_launch(void* const* d_in, const int* in_sizes, int n_in,
                              void* d_out, int out_size, void* d_ws, size_t ws_size,
                              hipStream_t stream) {
    const float* output  = (const float*)d_in[0];
    const float* target  = (const float*)d_in[1];
    const float* anchors = (const float*)d_in[2];

    float*    recG     = (float*)d_ws;                     // 12800 floats
    int*      nvArr    = (int*)(recG + kNB * kRECB);       // 16 ints
    float*    partials = (float*)(nvArr + 16);             // 320 floats
    unsigned* flags    = (unsigned*)(partials + kGRID);    // 320 uints

    k_targets<<<kNB, 64, 0, stream>>>(output, target, anchors, recG, nvArr);
    k_fused<<<kGRID, kBLK, 0, stream>>>(output, anchors, recG, nvArr, partials, flags, (float*)d_out);
}

// Round 10
// 16.068 us; speedup vs baseline: 1.1815x; 1.1815x over previous
//
#include <hip/hip_runtime.h>
#include <math.h>

// Problem constants
constexpr int kNB   = 16;
constexpr int kNA   = 5;
constexpr int kNC   = 80;
constexpr int kNH   = 64;
constexpr int kNW   = 64;
constexpr int kMAXT = 50;
constexpr int kCH    = 5 + kNC;          // 85
constexpr int kPLANE = kNH * kNW;        // 4096
constexpr int kCELLS_B = kNA * kPLANE;   // 20480
constexpr int kBLK  = 640;               // 10 waves
constexpr int kBPB  = kCELLS_B / kBLK;   // 32 blocks per batch
constexpr int kGRID = kNB * kBPB;        // 512 = exactly 2 blocks/CU
constexpr float kOBJ = 5.0f;
constexpr unsigned kREADY = 0x9E3779B9u; // != 0, != 0xAAAAAAAA poison

// LDS record layout (16 floats / target):
//  [0..3] x1,x2,y1,y2   [4] 0.6*garea  [5] cell(int bits)
//  [8..11] t0..t3       [12] tconf     [13] tcls
constexpr int kRECF = 16;
constexpr int kRECB = kMAXT * kRECF;

__device__ __forceinline__ float frcp(float x) { return __builtin_amdgcn_rcpf(x); }
__device__ __forceinline__ float fsig(float x) { return frcp(1.0f + __expf(-x)); }

__global__ __launch_bounds__(640, 5) void k_fused(const float* __restrict__ out,
                                                  const float* __restrict__ target,
                                                  const float* __restrict__ anchors,
                                                  float* __restrict__ partials,
                                                  unsigned* __restrict__ flags,
                                                  float* __restrict__ outv) {
    __shared__ __align__(16) float srec[kRECB];
    __shared__ int scell[kMAXT];
    __shared__ int snv;
    __shared__ float wred[10];

    const int tid  = threadIdx.x;
    const int wave = tid >> 6;
    const int lane = tid & 63;
    const int b    = blockIdx.x / kBPB;
    const int blkb = blockIdx.x % kBPB;      // 0..31 within batch

    // ---------- Phase 0: every thread issues its per-cell channel loads ----------
    const int cidx = blkb * kBLK + tid;      // within-batch cell (== mycell)
    const int a    = cidx >> 12;             // cidx / kPLANE
    const int remp = cidx & (kPLANE - 1);
    const int i    = remp & (kNW - 1), j = remp >> 6;
    const float* ob = out + ((size_t)(b * kNA + a) * kCH) * kPLANE + remp;
    float o0 = ob[0];
    float o1 = ob[kPLANE];
    float o2 = ob[2 * kPLANE];
    float o3 = ob[3 * kPLANE];
    float o4 = ob[4 * kPLANE];

    // ---------- Phase A (wave 0): LIGHT records only — one memory round trip ----------
    bool act = false;
    int cell = -1, gi = 0, gj = 0;
    float gx = 0, gy = 0, gw = 0, gh = 0, aw0 = 1.f, ah0 = 1.f;
    if (wave == 0) {
        int t = lane;
        float c0 = 0.f, x = 0.f, y = 0.f, w = 0.f, h = 0.f;
        if (t < kMAXT) {
            const float* tp = target + (b * kMAXT + t) * 5;
            c0 = tp[0]; x = tp[1]; y = tp[2]; w = tp[3]; h = tp[4];
        }
        unsigned long long m = __ballot(x != 0.0f);   // validity prefix (cumprod of x!=0)
        int nv = (int)__builtin_ctzll(~m);
        if (t == 0) snv = nv;
        act = (t < nv);
        if (act) {
            gx = x * kNW; gy = y * kNH; gw = w * kNW; gh = h * kNH;
            int bn = 0; float best = -1.0f;            // first max wins (jnp.argmax)
            for (int n = 0; n < kNA; ++n) {
                float aw_ = anchors[2 * n], ah_ = anchors[2 * n + 1];
                float inter = fminf(gw, aw_) * fminf(gh, ah_);
                float uni = gw * gh + aw_ * ah_ - inter;
                float r = inter * frcp(uni);
                if (r > best) { best = r; bn = n; }
            }
            aw0 = anchors[2 * bn]; ah0 = anchors[2 * bn + 1];
            gi = (int)gx; gi = gi < 0 ? 0 : (gi > kNW - 1 ? kNW - 1 : gi);
            gj = (int)gy; gj = gj < 0 ? 0 : (gj > kNH - 1 ? kNH - 1 : gj);
            cell = bn * kPLANE + gj * kNW + gi;

            float* r = srec + t * kRECF;
            r[0]  = gx - 0.5f * gw;  r[1]  = gx + 0.5f * gw;
            r[2]  = gy - 0.5f * gh;  r[3]  = gy + 0.5f * gh;
            r[4]  = 0.6f * gw * gh;  r[5]  = __int_as_float(cell);
            r[13] = c0;
        }
        if (t < kMAXT) scell[t] = act ? cell : -1;
    }
    __syncthreads();                         // barrier 1: light records ready
    const int nv = snv;

    // ---------- wave 0: issue matched-pred gather (overlaps with IoU loop below) -------
    float m0 = 0.f, m1 = 0.f, m2 = 0.f, m3 = 0.f;
    if (wave == 0 && act) {
        const float* mb = out + ((size_t)(b * kNA + (cell >> 12)) * kCH) * kPLANE + (cell & (kPLANE - 1));
        m0 = mb[0]; m1 = mb[kPLANE]; m2 = mb[2 * kPLANE]; m3 = mb[3 * kPLANE];
    }

    // ---------- waves 1-2: CE prep from staged cells (one read + one ballot) ----------
    float ceV0 = 0.f, ceV1 = -INFINITY, ceLt = 0.f;
    bool doCE = false;
    if (wave == 1 || wave == 2) {
        const int t_ce = blkb + kBPB * (wave - 1);     // 0..63 covers all 50
        int cellv = (lane < kMAXT) ? scell[lane] : -1;
        if (t_ce < nv) {
            int cellT = scell[t_ce];
            // owner = no later valid target maps to the same cell (last-write-wins)
            unsigned long long dup = __ballot(lane > t_ce && cellv == cellT);
            if (dup == 0ull) {
                doCE = true;
                int tcls = (int)srec[t_ce * kRECF + 13];
                const float* lg = out + ((size_t)(b * kNA + (cellT >> 12)) * kCH + 5) * kPLANE + (cellT & (kPLANE - 1));
                ceV0 = lg[(size_t)lane * kPLANE];
                if (lane < kNC - 64) ceV1 = lg[(size_t)(64 + lane) * kPLANE];
                ceLt = lg[(size_t)tcls * kPLANE];
            }
        }
    }

    // ---------- Phase C: per-cell loss (reads light record fields only) ----------
    float tx   = fsig(o0);
    float ty   = fsig(o1);
    float tw   = o2;
    float th   = o3;
    float conf = fsig(o4);

    float aw = anchors[2 * a], ah = anchors[2 * a + 1];
    float pw = __expf(tw) * aw, ph = __expf(th) * ah;
    float px = tx + (float)i, py = ty + (float)j;
    float px1 = px - 0.5f * pw, px2 = px + 0.5f * pw;
    float py1 = py - 0.5f * ph, py2 = py + 0.5f * ph;
    float p06 = 0.6f * pw * ph;

    // iou > 0.6  <=>  max_t(1.6*inter - 0.6*garea) > 0.6*parea
    float flag = -INFINITY;
    int match = -1;                           // last matching t wins (scatter semantics)
    for (int t = 0; t < nv; ++t) {
        const float4 bx = *reinterpret_cast<const float4*>(srec + t * kRECF);
        const float2 gc = *reinterpret_cast<const float2*>(srec + t * kRECF + 4);
        float cw  = fminf(bx.y, px2) - fmaxf(bx.x, px1);
        float chh = fminf(bx.w, py2) - fmaxf(bx.z, py1);
        float inter = fmaxf(cw, 0.f) * fmaxf(chh, 0.f);
        flag = fmaxf(flag, fmaf(1.6f, inter, -gc.x));
        match = (__float_as_int(gc.y) == cidx) ? t : match;
    }

    // ---------- wave 0: finish heavy record fields (gather has landed by now) ----------
    if (wave == 0 && act) {
        float mpx = fsig(m0) + (float)gi;
        float mpy = fsig(m1) + (float)gj;
        float mpw = __expf(m2) * aw0;
        float mph = __expf(m3) * ah0;
        float cw  = fminf(gx + 0.5f * gw, mpx + 0.5f * mpw) - fmaxf(gx - 0.5f * gw, mpx - 0.5f * mpw);
        float chh = fminf(gy + 0.5f * gh, mpy + 0.5f * mph) - fmaxf(gy - 0.5f * gh, mpy - 0.5f * mph);
        float inter = fmaxf(cw, 0.f) * fmaxf(chh, 0.f);
        float uni = gw * gh + mpw * mph - inter;
        float iou = (inter > 0.f) ? inter / uni : 0.f;

        float* r = srec + lane * kRECF;
        r[8]  = gx - (float)gi;  r[9]  = gy - (float)gj;
        r[10] = __logf(gw / aw0); r[11] = __logf(gh / ah0);
        r[12] = iou;
    }
    __syncthreads();                          // barrier 2: heavy fields ready

    float t0 = 0.5f, t1 = 0.5f, t2 = 0.f, t3 = 0.f, tconf = 0.f, cmask;
    if (match >= 0) {
        const float4 tt = *reinterpret_cast<const float4*>(srec + match * kRECF + 8);
        t0 = tt.x; t1 = tt.y; t2 = tt.z; t3 = tt.w;
        tconf = srec[match * kRECF + 12];
        cmask = kOBJ;
    } else {
        cmask = (flag > p06) ? 0.f : 1.f;
    }

    float dx = tx - t0, dy = ty - t1, dw = tw - t2, dh = th - t3, dc = conf - tconf;
    float loss = 0.5f * (dx * dx + dy * dy + dw * dw + dh * dh)
               + 0.5f * cmask * dc * dc;

    // ---------- Phase D: finish CE on waves 1-2 (wave-uniform per wave) ----------
    if (doCE) {
        float mx = fmaxf(ceV0, ceV1);
        #pragma unroll
        for (int off = 32; off > 0; off >>= 1) mx = fmaxf(mx, __shfl_xor(mx, off, 64));
        float s = __expf(ceV0 - mx) + ((lane < kNC - 64) ? __expf(ceV1 - mx) : 0.f);
        #pragma unroll
        for (int off = 32; off > 0; off >>= 1) s += __shfl_xor(s, off, 64);
        if (lane == 0) loss += __logf(s) + mx - ceLt;
    }

    // ---------- Phase E: block partial -> distinct-address flag handshake ----------
    #pragma unroll
    for (int off = 32; off > 0; off >>= 1) loss += __shfl_down(loss, off, 64);
    if (lane == 0) wred[wave] = loss;
    __syncthreads();
    if (tid == 0) {
        float v = 0.f;
        #pragma unroll
        for (int w = 0; w < 10; ++w) v += wred[w];     // fixed order
        __hip_atomic_store(&partials[blockIdx.x], v, __ATOMIC_RELAXED, __HIP_MEMORY_SCOPE_AGENT);
        __hip_atomic_store(&flags[blockIdx.x], kREADY, __ATOMIC_RELEASE, __HIP_MEMORY_SCOPE_AGENT);
    }

    // ---------- Phase F: block 0 gathers all partials (deterministic order) ----------
    if (blockIdx.x == 0) {
        __syncthreads();                                // protect wred reuse
        float v = 0.f;
        if (tid < kGRID) {
            while (__hip_atomic_load(&flags[tid], __ATOMIC_ACQUIRE, __HIP_MEMORY_SCOPE_AGENT) != kREADY)
                __builtin_amdgcn_s_sleep(2);
            v = __hip_atomic_load(&partials[tid], __ATOMIC_RELAXED, __HIP_MEMORY_SCOPE_AGENT);
            // reset for the next call (stream-ordered; no overlap between calls)
            __hip_atomic_store(&flags[tid], 0u, __ATOMIC_RELAXED, __HIP_MEMORY_SCOPE_AGENT);
        }
        #pragma unroll
        for (int off = 32; off > 0; off >>= 1) v += __shfl_down(v, off, 64);
        if (lane == 0) wred[wave] = v;
        __syncthreads();
        if (tid == 0) {
            float s = 0.f;
            #pragma unroll
            for (int w = 0; w < 10; ++w) s += wred[w];  // fixed order
            outv[0] = s;
        }
    }
}

extern "C" void kernel_launch(void* const* d_in, const int* in_sizes, int n_in,
                              void* d_out, int out_size, void* d_ws, size_t ws_size,
                              hipStream_t stream) {
    const float* output  = (const float*)d_in[0];
    const float* target  = (const float*)d_in[1];
    const float* anchors = (const float*)d_in[2];

    float*    partials = (float*)d_ws;                  // 512 floats
    unsigned* flags    = (unsigned*)(partials + kGRID); // 512 uints

    k_fused<<<kGRID, kBLK, 0, stream>>>(output, target, anchors, partials, flags, (float*)d_out);
}

// Round 11
// 15.495 us; speedup vs baseline: 1.2252x; 1.0370x over previous
//
#include <hip/hip_runtime.h>
#include <math.h>

// Problem constants
constexpr int kNB   = 16;
constexpr int kNA   = 5;
constexpr int kNC   = 80;
constexpr int kNH   = 64;
constexpr int kNW   = 64;
constexpr int kMAXT = 50;
constexpr int kCH    = 5 + kNC;          // 85
constexpr int kPLANE = kNH * kNW;        // 4096
constexpr int kCELLS_B = kNA * kPLANE;   // 20480
constexpr int kBLK  = 1024;              // 16 waves (R8 geometry — best so far)
constexpr int kBPB  = kCELLS_B / kBLK;   // 20 blocks per batch
constexpr int kGRID = kNB * kBPB;        // 320
constexpr float kOBJ = 5.0f;
constexpr unsigned kREADY = 0x9E3779B9u; // != 0, != 0xAAAAAAAA poison

// LDS record layout (16 floats / target):
//  [0..3] x1,x2,y1,y2   [4] 0.6*garea  [5] cell(int bits)
//  [8..11] t0..t3       [12] tconf     [13] tcls
constexpr int kRECF = 16;
constexpr int kRECB = kMAXT * kRECF;

__device__ __forceinline__ float frcp(float x) { return __builtin_amdgcn_rcpf(x); }
__device__ __forceinline__ float fsig(float x) { return frcp(1.0f + __expf(-x)); }

__global__ __launch_bounds__(1024) void k_fused(const float* __restrict__ out,
                                                const float* __restrict__ target,
                                                const float* __restrict__ anchors,
                                                float* __restrict__ partials,
                                                unsigned* __restrict__ flags,
                                                float* __restrict__ outv) {
    __shared__ __align__(16) float srec[kRECB];
    __shared__ int scell[kMAXT];
    __shared__ int snv;
    __shared__ float wred[16];

    const int tid  = threadIdx.x;
    const int wave = tid >> 6;
    const int lane = tid & 63;
    const int b    = blockIdx.x / kBPB;
    const int blkb = blockIdx.x % kBPB;      // 0..19 within batch

    // ---------- Phase 0: every thread issues its per-cell channel loads ----------
    const int cidx = blkb * kBLK + tid;      // within-batch cell (== mycell)
    const int a    = cidx >> 12;             // block-uniform
    const int remp = cidx & (kPLANE - 1);
    const int i    = remp & (kNW - 1), j = remp >> 6;
    const float* ob = out + ((size_t)(b * kNA + a) * kCH) * kPLANE + remp;
    float o0 = ob[0];
    float o1 = ob[kPLANE];
    float o2 = ob[2 * kPLANE];
    float o3 = ob[3 * kPLANE];
    float o4 = ob[4 * kPLANE];

    // ---------- Phase A (wave 0): LIGHT record fields — ONE memory round trip ----------
    bool act = false;
    int cell = -1, gi = 0, gj = 0;
    float gx = 0, gy = 0, gw = 0, gh = 0, aw0 = 1.f, ah0 = 1.f;
    if (wave == 0) {
        int t = lane;
        float c0 = 0.f, x = 0.f, y = 0.f, w = 0.f, h = 0.f;
        if (t < kMAXT) {
            const float* tp = target + (b * kMAXT + t) * 5;
            c0 = tp[0]; x = tp[1]; y = tp[2]; w = tp[3]; h = tp[4];
        }
        unsigned long long m = __ballot(x != 0.0f);   // validity prefix (cumprod of x!=0)
        int nv = (int)__builtin_ctzll(~m);
        if (t == 0) snv = nv;
        act = (t < nv);
        if (act) {
            gx = x * kNW; gy = y * kNH; gw = w * kNW; gh = h * kNH;
            int bn = 0; float best = -1.0f;            // first max wins (jnp.argmax)
            for (int n = 0; n < kNA; ++n) {
                float aw_ = anchors[2 * n], ah_ = anchors[2 * n + 1];
                float inter = fminf(gw, aw_) * fminf(gh, ah_);
                float uni = gw * gh + aw_ * ah_ - inter;
                float r = inter / uni;
                if (r > best) { best = r; bn = n; }
            }
            aw0 = anchors[2 * bn]; ah0 = anchors[2 * bn + 1];
            gi = (int)gx; gi = gi < 0 ? 0 : (gi > kNW - 1 ? kNW - 1 : gi);
            gj = (int)gy; gj = gj < 0 ? 0 : (gj > kNH - 1 ? kNH - 1 : gj);
            cell = bn * kPLANE + gj * kNW + gi;

            float* r = srec + t * kRECF;
            r[0]  = gx - 0.5f * gw;  r[1]  = gx + 0.5f * gw;
            r[2]  = gy - 0.5f * gh;  r[3]  = gy + 0.5f * gh;
            r[4]  = 0.6f * gw * gh;  r[5]  = __int_as_float(cell);
            r[13] = c0;
        }
        if (t < kMAXT) scell[t] = act ? cell : -1;
    }
    __syncthreads();                         // barrier 1: light records + scell ready
    const int nv = snv;

    // ---------- wave 0: issue matched-pred gather (latency hides under IoU loop) -------
    float m0 = 0.f, m1 = 0.f, m2 = 0.f, m3 = 0.f;
    if (wave == 0 && act) {
        const float* mb = out + ((size_t)(b * kNA + (cell >> 12)) * kCH) * kPLANE + (cell & (kPLANE - 1));
        m0 = mb[0]; m1 = mb[kPLANE]; m2 = mb[2 * kPLANE]; m3 = mb[3 * kPLANE];
    }

    // ---------- waves 1-3: CE prep from scell (one LDS read + one ballot) ----------
    float ceV0 = 0.f, ceV1 = -INFINITY, ceLt = 0.f;
    bool doCE = false;
    if (wave >= 1 && wave <= 3) {
        const int t_ce = blkb + kBPB * (wave - 1);     // 0..59 covers all 50
        int cellv = (lane < kMAXT) ? scell[lane] : -1;
        if (t_ce < nv) {
            int cellT = scell[t_ce];
            // owner = no later valid target maps to the same cell (last-write-wins)
            unsigned long long dup = __ballot(lane > t_ce && cellv == cellT);
            if (dup == 0ull) {
                doCE = true;
                int tcls = (int)srec[t_ce * kRECF + 13];
                const float* lg = out + ((size_t)(b * kNA + (cellT >> 12)) * kCH + 5) * kPLANE + (cellT & (kPLANE - 1));
                ceV0 = lg[(size_t)lane * kPLANE];
                if (lane < kNC - 64) ceV1 = lg[(size_t)(64 + lane) * kPLANE];
                ceLt = lg[(size_t)tcls * kPLANE];
            }
        }
    }

    // ---------- Phase C: per-cell loss (reads light record fields only) ----------
    float tx   = fsig(o0);
    float ty   = fsig(o1);
    float tw   = o2;
    float th   = o3;
    float conf = fsig(o4);

    float aw = anchors[2 * a], ah = anchors[2 * a + 1];
    float pw = __expf(tw) * aw, ph = __expf(th) * ah;
    float px = tx + (float)i, py = ty + (float)j;
    float px1 = px - 0.5f * pw, px2 = px + 0.5f * pw;
    float py1 = py - 0.5f * ph, py2 = py + 0.5f * ph;
    float p06 = 0.6f * pw * ph;

    // iou > 0.6  <=>  max_t(1.6*inter - 0.6*garea) > 0.6*parea
    float flag = -INFINITY;
    int match = -1;                           // last matching t wins (scatter semantics)
    for (int t = 0; t < nv; ++t) {
        const float4 bx = *reinterpret_cast<const float4*>(srec + t * kRECF);
        const float2 gc = *reinterpret_cast<const float2*>(srec + t * kRECF + 4);
        float cw  = fminf(bx.y, px2) - fmaxf(bx.x, px1);
        float chh = fminf(bx.w, py2) - fmaxf(bx.z, py1);
        float inter = fmaxf(cw, 0.f) * fmaxf(chh, 0.f);
        flag = fmaxf(flag, fmaf(1.6f, inter, -gc.x));
        match = (__float_as_int(gc.y) == cidx) ? t : match;
    }

    // ---------- wave 0: finish heavy record fields (gather has landed by now) ----------
    if (wave == 0 && act) {
        float mpx = fsig(m0) + (float)gi;
        float mpy = fsig(m1) + (float)gj;
        float mpw = __expf(m2) * aw0;
        float mph = __expf(m3) * ah0;
        float cw  = fminf(gx + 0.5f * gw, mpx + 0.5f * mpw) - fmaxf(gx - 0.5f * gw, mpx - 0.5f * mpw);
        float chh = fminf(gy + 0.5f * gh, mpy + 0.5f * mph) - fmaxf(gy - 0.5f * gh, mpy - 0.5f * mph);
        float inter = fmaxf(cw, 0.f) * fmaxf(chh, 0.f);
        float uni = gw * gh + mpw * mph - inter;
        float iou = (inter > 0.f) ? inter / uni : 0.f;

        float* r = srec + lane * kRECF;
        r[8]  = gx - (float)gi;   r[9]  = gy - (float)gj;
        r[10] = __logf(gw / aw0); r[11] = __logf(gh / ah0);
        r[12] = iou;
    }
    __syncthreads();                          // barrier 2: heavy fields ready

    float t0 = 0.5f, t1 = 0.5f, t2 = 0.f, t3 = 0.f, tconf = 0.f, cmask;
    if (match >= 0) {
        const float4 tt = *reinterpret_cast<const float4*>(srec + match * kRECF + 8);
        t0 = tt.x; t1 = tt.y; t2 = tt.z; t3 = tt.w;
        tconf = srec[match * kRECF + 12];
        cmask = kOBJ;
    } else {
        cmask = (flag > p06) ? 0.f : 1.f;
    }

    float dx = tx - t0, dy = ty - t1, dw = tw - t2, dh = th - t3, dc = conf - tconf;
    float loss = 0.5f * (dx * dx + dy * dy + dw * dw + dh * dh)
               + 0.5f * cmask * dc * dc;

    // ---------- Phase D: finish CE on waves 1-3 (wave-uniform per wave) ----------
    if (doCE) {
        float mx = fmaxf(ceV0, ceV1);
        #pragma unroll
        for (int off = 32; off > 0; off >>= 1) mx = fmaxf(mx, __shfl_xor(mx, off, 64));
        float s = __expf(ceV0 - mx) + ((lane < kNC - 64) ? __expf(ceV1 - mx) : 0.f);
        #pragma unroll
        for (int off = 32; off > 0; off >>= 1) s += __shfl_xor(s, off, 64);
        if (lane == 0) loss += __logf(s) + mx - ceLt;
    }

    // ---------- Phase E: block partial -> distinct-address flag handshake ----------
    #pragma unroll
    for (int off = 32; off > 0; off >>= 1) loss += __shfl_down(loss, off, 64);
    if (lane == 0) wred[wave] = loss;
    __syncthreads();
    if (tid == 0) {
        float v = 0.f;
        #pragma unroll
        for (int w = 0; w < 16; ++w) v += wred[w];     // fixed order
        __hip_atomic_store(&partials[blockIdx.x], v, __ATOMIC_RELAXED, __HIP_MEMORY_SCOPE_AGENT);
        __hip_atomic_store(&flags[blockIdx.x], kREADY, __ATOMIC_RELEASE, __HIP_MEMORY_SCOPE_AGENT);
    }

    // ---------- Phase F: block 0 gathers all partials (deterministic order) ----------
    if (blockIdx.x == 0) {
        __syncthreads();                                // protect wred reuse
        float v = 0.f;
        if (tid < kGRID) {
            while (__hip_atomic_load(&flags[tid], __ATOMIC_ACQUIRE, __HIP_MEMORY_SCOPE_AGENT) != kREADY)
                __builtin_amdgcn_s_sleep(2);
            v = __hip_atomic_load(&partials[tid], __ATOMIC_RELAXED, __HIP_MEMORY_SCOPE_AGENT);
            // reset for the next call (stream-ordered; no overlap between calls)
            __hip_atomic_store(&flags[tid], 0u, __ATOMIC_RELAXED, __HIP_MEMORY_SCOPE_AGENT);
        }
        #pragma unroll
        for (int off = 32; off > 0; off >>= 1) v += __shfl_down(v, off, 64);
        if (lane == 0) wred[wave] = v;
        __syncthreads();
        if (tid == 0) {
            float s = 0.f;
            #pragma unroll
            for (int w = 0; w < 16; ++w) s += wred[w];  // fixed order (only waves 0-4 nonzero)
            outv[0] = s;
        }
    }
}

extern "C" void kernel_launch(void* const* d_in, const int* in_sizes, int n_in,
                              void* d_out, int out_size, void* d_ws, size_t ws_size,
                              hipStream_t stream) {
    const float* output  = (const float*)d_in[0];
    const float* target  = (const float*)d_in[1];
    const float* anchors = (const float*)d_in[2];

    float*    partials = (float*)d_ws;                  // 320 floats
    unsigned* flags    = (unsigned*)(partials + kGRID); // 320 uints

    k_fused<<<kGRID, kBLK, 0, stream>>>(output, target, anchors, partials, flags, (float*)d_out);
}